// Round 1
// baseline (412.659 us; speedup 1.0000x reference)
//
#include <hip/hip_runtime.h>
#include <math.h>

// RBFController: B=2048 batch, N=32 centers, D=64 dims, A=8 actions.
// One 256-thread block per batch element. Two SPD 64x64 LDL^T factorizations
// in per-thread 4x4 register tiles (LDS only for column exchange + factored L).
// Wave-synchronous triangular solves: 8 lanes/RHS, x in registers, shfl broadcast.

#define DD 64
#define NN 32
#define AA 8
#define NBATCH 2048
#define STR 68   // LDS row stride for L matrices: 68*4B=272 ≡ 0 mod 16 -> b128-aligned rows

// ---------------- prep: exp1[n][m] table + logdet_lh scalar ----------------
__global__ void rbf_prep(const float* __restrict__ centers,
                         const float* __restrict__ ls,
                         float* __restrict__ ws) {
    int t = threadIdx.x;
    int p = blockIdx.x * 256 + t;          // pair id 0..1023
    if (p < NN * NN) {
        int n = p >> 5, m = p & 31;
        float acc = 0.f;
        for (int d = 0; d < DD; ++d) {
            float l = ls[d];
            float df = centers[n * DD + d] - centers[m * DD + d];
            acc += df * df / (l * l);
        }
        ws[p] = -0.25f * acc;              // exp1[n][m]
    }
    if (blockIdx.x == 0 && t < DD) {
        float l = ls[t];
        float v = logf(0.5f * l * l);
        #pragma unroll
        for (int o = 1; o < 64; o <<= 1) v += __shfl_xor(v, o, 64);
        if (t == 0) ws[NN * NN] = v;       // logdet_lh = sum log(l^2/2)
    }
}

// ---------------- main kernel ----------------
__global__ __launch_bounds__(256) void rbf_main(
    const float* __restrict__ mean,      // (B,64)
    const float* __restrict__ cov,       // (B,64,64)
    const float* __restrict__ centers,   // (32,64)
    const float* __restrict__ weights,   // (32,8)
    const float* __restrict__ ls,        // (64,)
    const float* __restrict__ ws,        // exp1[1024], logdet_lh at [1024]
    float* __restrict__ out)
{
    __shared__ __align__(16) float LmT1[DD * STR];  // L1^T (row k = column k of L1), upper+diag zero-filled
    __shared__ __align__(16) float BUF2[DD * STR];  // L2^T during factor/fwd2; later L1 (transposed) for bwd
    __shared__ __align__(16) float cen_s[NN * DD];
    __shared__ __align__(16) float H_s[NN * STR];   // h_n = D2^{-1/2} L2^{-1} r_n
    __shared__ __align__(16) float K_s[DD * AA];
    __shared__ __align__(16) float cp_s[DD * AA];   // cross_pre = invl * B1^{-1} K
    __shared__ __align__(16) float col1[DD];
    __shared__ __align__(16) float col2[DD];
    __shared__ float diag1[DD], invd1[DD], diag2[DD], rsd2[DD];
    __shared__ float mean_s[DD], invl_s[DD], l2h_s[DD];
    __shared__ float w_s[NN * AA], phiw_s[NN * AA], U_s[NN * AA];
    __shared__ float am_s[AA], acov_s[AA * AA], acr_s[AA * AA], Ca_s[AA];
    __shared__ float scal_s[4];   // [0]=logdet1 [1]=logdet2 [2]=logdet_lh

    const int t   = threadIdx.x;
    const int b   = blockIdx.x;
    const int rb  = t >> 4;   // tile rows 4rb..4rb+3 (wave w owns rows 16w..16w+15)
    const int cbl = t & 15;   // tile cols 4cbl..4cbl+3
    const int w64 = t & 63;
    const int grp = t >> 3;   // RHS group 0..31
    const int l8  = t & 7;    // lane-in-group; owns rows 8*l8..8*l8+7 in solves

    // ---- stage small arrays ----
    if (t < DD) {
        float l = ls[t];
        invl_s[t] = 1.0f / l;
        l2h_s[t]  = 0.5f * l * l;
        mean_s[t] = mean[(size_t)b * DD + t];
    }
    w_s[t] = weights[t];                       // NN*AA == 256
    for (int e = t; e < NN * DD; e += 256) cen_s[e] = centers[e];
    if (t == 0) scal_s[2] = ws[NN * NN];
    __syncthreads();

    // ---- build register tiles: A1 = Dl cov Dl + I ; A2 = cov + diag(l^2/2) ----
    float A1[4][4], A2[4][4];
    {
        const float* cvb = cov + (size_t)b * DD * DD;
        #pragma unroll
        for (int s = 0; s < 4; ++s) {
            int r = 4 * rb + s;
            const float4 cv = *(const float4*)(cvb + (size_t)r * DD + 4 * cbl);
            float ir = invl_s[r];
            int c0 = 4 * cbl;
            A1[s][0] = cv.x * ir * invl_s[c0 + 0] + ((r == c0 + 0) ? 1.0f : 0.0f);
            A1[s][1] = cv.y * ir * invl_s[c0 + 1] + ((r == c0 + 1) ? 1.0f : 0.0f);
            A1[s][2] = cv.z * ir * invl_s[c0 + 2] + ((r == c0 + 2) ? 1.0f : 0.0f);
            A1[s][3] = cv.w * ir * invl_s[c0 + 3] + ((r == c0 + 3) ? 1.0f : 0.0f);
            A2[s][0] = cv.x + ((r == c0 + 0) ? l2h_s[r] : 0.0f);
            A2[s][1] = cv.y + ((r == c0 + 1) ? l2h_s[r] : 0.0f);
            A2[s][2] = cv.z + ((r == c0 + 2) ? l2h_s[r] : 0.0f);
            A2[s][3] = cv.w + ((r == c0 + 3) ? l2h_s[r] : 0.0f);
        }
    }

    // ---- fused LDL^T factorization of both matrices (right-looking) ----
    for (int j = 0; j < DD; ++j) {
        // phase A: owners of column j dump current column to colbuf
        if (cbl == (j >> 2)) {
            int c = j & 3;
            #pragma unroll
            for (int s = 0; s < 4; ++s) {
                int r = 4 * rb + s;
                if (r >= j) {
                    col1[r] = (c == 0) ? A1[s][0] : (c == 1) ? A1[s][1] : (c == 2) ? A1[s][2] : A1[s][3];
                    col2[r] = (c == 0) ? A2[s][0] : (c == 1) ? A2[s][1] : (c == 2) ? A2[s][2] : A2[s][3];
                }
            }
        }
        __syncthreads();
        // phase B
        float d1v = col1[j], d2v = col2[j];
        float id1 = __builtin_amdgcn_rcpf(d1v);   // ~1ulp; backward-stable enough (cond ~ 1)
        float id2 = __builtin_amdgcn_rcpf(d2v);
        if (t < DD) {                              // wave 0: write L1^T row j (zeros for i<=j)
            LmT1[j * STR + t] = (t > j) ? col1[t] * id1 : 0.0f;
            if (t == 0) { diag1[j] = d1v; invd1[j] = id1; }
        } else if (t < 2 * DD) {                   // wave 1: write L2^T row j
            int i = t - DD;
            BUF2[j * STR + i] = (i > j) ? col2[i] * id2 : 0.0f;
            if (i == 0) diag2[j] = d2v;
        }
        if (4 * rb + 3 > j && 4 * cbl + 3 > j) {   // trailing Schur update (rank-1)
            float fr1[4], fr2[4], h1[4], h2[4];
            #pragma unroll
            for (int s = 0; s < 4; ++s) {
                int r = 4 * rb + s;
                bool m = r > j;
                fr1[s] = m ? col1[r] : 0.0f;
                fr2[s] = m ? col2[r] : 0.0f;
            }
            #pragma unroll
            for (int c = 0; c < 4; ++c) {
                int cc = 4 * cbl + c;
                bool m = cc > j;
                h1[c] = m ? col1[cc] * id1 : 0.0f;
                h2[c] = m ? col2[cc] * id2 : 0.0f;
            }
            #pragma unroll
            for (int s = 0; s < 4; ++s) {
                #pragma unroll
                for (int c = 0; c < 4; ++c) {
                    A1[s][c] -= fr1[s] * h1[c];
                    A2[s][c] -= fr2[s] * h2[c];
                }
            }
        }
        __syncthreads();
    }

    // ---- logdets + rsqrt(d2) ----
    if (t < DD) {
        float v = logf(diag1[t]);
        #pragma unroll
        for (int o = 1; o < 64; o <<= 1) v += __shfl_xor(v, o, 64);
        if (t == 0) scal_s[0] = v;
    } else if (t < 2 * DD) {
        int i = t - DD;
        float dv = diag2[i];
        rsd2[i] = 1.0f / sqrtf(dv);
        float v = logf(dv);
        #pragma unroll
        for (int o = 1; o < 64; o <<= 1) v += __shfl_xor(v, o, 64);
        if (i == 0) scal_s[1] = v;
    }
    __syncthreads();

    // ---- forward solve system 1 (32 RHS), phi from quadform ----
    float x[8];
    #pragma unroll
    for (int s = 0; s < 8; ++s) {
        int i = 8 * l8 + s;
        x[s] = (cen_s[grp * DD + i] - mean_s[i]) * invl_s[i];
    }
    for (int k8 = 0; k8 < 8; ++k8) {
        #pragma unroll
        for (int kk = 0; kk < 8; ++kk) {
            int k = 8 * k8 + kk;
            float zk = __shfl(x[kk], (w64 & 56) | k8, 64);
            #pragma unroll
            for (int s = 0; s < 8; ++s)
                x[s] -= LmT1[k * STR + 8 * l8 + s] * zk;   // zero-filled => unpredicated
        }
    }
    {
        float qf = 0.f;
        #pragma unroll
        for (int s = 0; s < 8; ++s) qf += x[s] * x[s] * invd1[8 * l8 + s];
        qf += __shfl_xor(qf, 1, 64);
        qf += __shfl_xor(qf, 2, 64);
        qf += __shfl_xor(qf, 4, 64);
        float ph = expf(-0.5f * (scal_s[0] + qf));   // normalizer * exp_term
        phiw_s[grp * AA + l8] = ph * w_s[grp * AA + l8];
    }

    // ---- forward solve system 2 (32 RHS), dump H ----
    #pragma unroll
    for (int s = 0; s < 8; ++s) {
        int i = 8 * l8 + s;
        x[s] = 0.5f * (cen_s[grp * DD + i] - mean_s[i]);   // r_n
    }
    for (int k8 = 0; k8 < 8; ++k8) {
        #pragma unroll
        for (int kk = 0; kk < 8; ++kk) {
            int k = 8 * k8 + kk;
            float zk = __shfl(x[kk], (w64 & 56) | k8, 64);
            #pragma unroll
            for (int s = 0; s < 8; ++s)
                x[s] -= BUF2[k * STR + 8 * l8 + s] * zk;
        }
    }
    #pragma unroll
    for (int s = 0; s < 8; ++s) {
        int i = 8 * l8 + s;
        H_s[grp * STR + i] = x[s] * rsd2[i];
    }
    __syncthreads();

    // ---- Gram / Q / U=Q*w ; K build ; transpose L1 into BUF2 ----
    {
        float acc[4] = {0.f, 0.f, 0.f, 0.f};
        for (int e = 0; e < 16; ++e) {
            const float4 hn = *(const float4*)&H_s[grp * STR + 4 * e];
            #pragma unroll
            for (int mm = 0; mm < 4; ++mm) {
                const float4 hm = *(const float4*)&H_s[(4 * l8 + mm) * STR + 4 * e];
                float s0 = hn.x + hm.x, s1 = hn.y + hm.y;
                float s2 = hn.z + hm.z, s3 = hn.w + hm.w;
                acc[mm] += s0 * s0 + s1 * s1 + s2 * s2 + s3 * s3;  // |h_n+h_m|^2
            }
        }
        float cq = expf(0.5f * (scal_s[2] - scal_s[1]));
        const float4 e1 = *(const float4*)&ws[grp * NN + 4 * l8];
        float e1a[4] = {e1.x, e1.y, e1.z, e1.w};
        float u[8] = {0.f, 0.f, 0.f, 0.f, 0.f, 0.f, 0.f, 0.f};
        #pragma unroll
        for (int mm = 0; mm < 4; ++mm) {
            float Q = cq * expf(e1a[mm] - 0.5f * acc[mm]);
            int m = 4 * l8 + mm;
            #pragma unroll
            for (int a = 0; a < AA; ++a) u[a] += Q * w_s[m * AA + a];
        }
        #pragma unroll
        for (int a = 0; a < AA; ++a) {
            u[a] += __shfl_xor(u[a], 1, 64);
            u[a] += __shfl_xor(u[a], 2, 64);
            u[a] += __shfl_xor(u[a], 4, 64);
        }
        float uv = (l8 == 0) ? u[0] : (l8 == 1) ? u[1] : (l8 == 2) ? u[2] : (l8 == 3) ? u[3]
                 : (l8 == 4) ? u[4] : (l8 == 5) ? u[5] : (l8 == 6) ? u[6] : u[7];
        U_s[grp * AA + l8] = uv;
    }
    {   // K[d][a] = sum_n s_n[d] * phiw[n][a]
        int d = t >> 2, a0 = (t & 3) * 2;
        float md = mean_s[d], il = invl_s[d];
        float k0 = 0.f, k1 = 0.f;
        for (int n = 0; n < NN; ++n) {
            float sv = (cen_s[n * DD + d] - md) * il;
            k0 += sv * phiw_s[n * AA + a0];
            k1 += sv * phiw_s[n * AA + a0 + 1];
        }
        K_s[d * AA + a0]     = k0;
        K_s[d * AA + a0 + 1] = k1;
    }
    for (int e = 0; e < 16; ++e) {   // BUF2 <- L1 (rows), for backward solve
        int idx = t + 256 * e;
        int k = idx >> 6, i = idx & 63;
        BUF2[i * STR + k] = LmT1[k * STR + i];
    }
    __syncthreads();

    // ---- parallel: wave0 = 8-RHS solve; wave1 lanes 0..7 = amean; wave2 = W^T U ----
    if (t < 64) {
        float y[8];
        int aa_ = t >> 3;
        #pragma unroll
        for (int s = 0; s < 8; ++s) y[s] = K_s[(8 * l8 + s) * AA + aa_];
        for (int k8 = 0; k8 < 8; ++k8) {               // forward (L1, unit diag)
            #pragma unroll
            for (int kk = 0; kk < 8; ++kk) {
                int k = 8 * k8 + kk;
                float zk = __shfl(y[kk], (t & 56) | k8, 64);
                #pragma unroll
                for (int s = 0; s < 8; ++s) y[s] -= LmT1[k * STR + 8 * l8 + s] * zk;
            }
        }
        #pragma unroll
        for (int s = 0; s < 8; ++s) y[s] *= invd1[8 * l8 + s];
        for (int k8 = 7; k8 >= 0; --k8) {              // backward (L1^T)
            #pragma unroll
            for (int kk = 7; kk >= 0; --kk) {
                int k = 8 * k8 + kk;
                float tk = __shfl(y[kk], (t & 56) | k8, 64);
                #pragma unroll
                for (int s = 0; s < 8; ++s) y[s] -= BUF2[k * STR + 8 * l8 + s] * tk;
            }
        }
        #pragma unroll
        for (int s = 0; s < 8; ++s) {
            int i = 8 * l8 + s;
            cp_s[i * AA + aa_] = y[s] * invl_s[i];
        }
    } else if (t < 72) {
        int a = t - 64;
        float am = 0.f;
        for (int n = 0; n < NN; ++n) am += phiw_s[n * AA + a];
        am_s[a] = am;
    } else if (t >= 128 && t < 192) {
        int t2 = t - 128, a = t2 >> 3, c = t2 & 7;
        float acc = 0.f;
        for (int n = 0; n < NN; ++n) acc += w_s[n * AA + a] * U_s[n * AA + c];
        acr_s[t2] = acc;
    }
    __syncthreads();

    // ---- final pre-squash action_cov ----
    if (t < 64) {
        int a = t >> 3, c = t & 7;
        float val = 0.5f * (acr_s[a * AA + c] + acr_s[c * AA + a])
                  - am_s[a] * am_s[c]
                  + ((a == c) ? 1e-6f : 0.0f);
        acov_s[t] = val;
    }
    __syncthreads();

    // ---- squash + outputs ----
    float* out0 = out;
    float* out1 = out + (size_t)NBATCH * AA;
    float* out2 = out + (size_t)NBATCH * AA + (size_t)NBATCH * AA * AA;
    if (t < 64) {
        int a = t >> 3, c = t & 7;
        float ama = am_s[a], amc = am_s[c];
        float dca = acov_s[a * AA + a], dcc = acov_s[c * AA + c];
        float v = acov_s[t];
        float q = expf(-0.5f * (dca + dcc));
        // expm1 formulation: avoids catastrophic cancellation at v ~ 1e-6
        float sq = 0.5f * q * (expm1f(v) * cosf(ama - amc) - expm1f(-v) * cosf(ama + amc));
        out1[(size_t)b * 64 + t] = sq;
        if (t < AA) {
            float e = expf(-0.5f * acov_s[t * AA + t]);
            out0[(size_t)b * AA + t] = e * sinf(am_s[t]);
            Ca_s[t] = e * cosf(am_s[t]);
        }
    }
    __syncthreads();
    #pragma unroll
    for (int e = 0; e < 2; ++e) {
        int idx = t + 256 * e;
        out2[(size_t)b * 512 + idx] = cp_s[idx] * Ca_s[idx & 7];
    }
}

extern "C" void kernel_launch(void* const* d_in, const int* in_sizes, int n_in,
                              void* d_out, int out_size, void* d_ws, size_t ws_size,
                              hipStream_t stream) {
    (void)in_sizes; (void)n_in; (void)out_size; (void)ws_size;
    const float* mean    = (const float*)d_in[0];
    const float* cov     = (const float*)d_in[1];
    const float* centers = (const float*)d_in[2];
    const float* weights = (const float*)d_in[3];
    const float* ls      = (const float*)d_in[4];
    float* ws  = (float*)d_ws;
    float* o   = (float*)d_out;
    rbf_prep<<<4, 256, 0, stream>>>(centers, ls, ws);
    rbf_main<<<NBATCH, 256, 0, stream>>>(mean, cov, centers, weights, ls, ws, o);
}